// Round 1
// 1567.586 us; speedup vs baseline: 2.8720x; 2.8720x over previous
//
#include <hip/hip_runtime.h>

// Scatter-mean: out[n, :] = sum_{e: index[e]==n} msg[e, :] / max(count[n], 1)
// E = 2,000,000 edges, D = 128, N = 100,000 segments.
//
// Round 2 strategy: the old path spent 3.4 ms in 256M fp32 global atomics
// (74 G atomics/s TCC serialization ceiling; WRITE_SIZE showed 4.16 GB of
// line-granular RMW traffic for a 1.02 GB payload). Replace with counting-sort
// binning + per-segment gather-reduce:
//   1. histogram counts per segment          (2M int atomics)
//   2. exclusive scan of counts -> offsets   (block scan + bsum scan + add)
//   3. scatter edge ids into bins            (2M int atomics + 8 MB writes)
//   4. one wave per segment: gather rows (512 B coalesced each), accumulate
//      in registers, scale by 1/max(c,1), single coalesced row write.
// Data moved ~1.1 GB total; atomics drop 256M -> 4M.

#define D 128
#define D2 (D / 2)   // 64 float2 per row: one row == one wave-wide float2 load
#define D4 (D / 4)

// ---------- Pass 1: histogram ----------
__global__ __launch_bounds__(256) void hist_kernel(
    const int* __restrict__ index, int* __restrict__ cnt, int E) {
    int e = blockIdx.x * 256 + threadIdx.x;
    if (e < E) atomicAdd(&cnt[index[e]], 1);
}

// ---------- Pass 2: exclusive scan of cnt[0..N) into off[0..N) ----------
__global__ __launch_bounds__(1024) void scan_block_kernel(
    const int* __restrict__ cnt, int* __restrict__ off,
    int* __restrict__ bsum, int N) {
    __shared__ int s[1024];
    int t = threadIdx.x;
    int g = blockIdx.x * 1024 + t;
    int v = (g < N) ? cnt[g] : 0;
    s[t] = v;
    __syncthreads();
    #pragma unroll
    for (int d = 1; d < 1024; d <<= 1) {
        int x = (t >= d) ? s[t - d] : 0;
        __syncthreads();
        s[t] += x;
        __syncthreads();
    }
    if (g < N) off[g] = s[t] - v;                 // exclusive within block
    if (t == 1023) bsum[blockIdx.x] = s[1023];    // block total
}

__global__ __launch_bounds__(1024) void scan_bsum_kernel(
    int* __restrict__ bsum, int NB) {
    // NB <= 1024 (N <= 1M). Single-block exclusive scan, in place.
    __shared__ int s[1024];
    int t = threadIdx.x;
    int v = (t < NB) ? bsum[t] : 0;
    s[t] = v;
    __syncthreads();
    #pragma unroll
    for (int d = 1; d < 1024; d <<= 1) {
        int x = (t >= d) ? s[t - d] : 0;
        __syncthreads();
        s[t] += x;
        __syncthreads();
    }
    if (t < NB) bsum[t] = s[t] - v;
}

__global__ __launch_bounds__(256) void scan_add_kernel(
    int* __restrict__ off, const int* __restrict__ bsum,
    int* __restrict__ cur, int N) {
    int g = blockIdx.x * 256 + threadIdx.x;
    if (g < N) {
        int o = off[g] + bsum[g >> 10];
        off[g] = o;       // global exclusive offset (segment start)
        cur[g] = o;       // scatter cursor copy
    }
}

// ---------- Pass 3: scatter edge ids into bins ----------
__global__ __launch_bounds__(256) void scatter_perm_kernel(
    const int* __restrict__ index, int* __restrict__ cur,
    int* __restrict__ perm, int E) {
    int e = blockIdx.x * 256 + threadIdx.x;
    if (e < E) {
        int p = atomicAdd(&cur[index[e]], 1);
        perm[p] = e;
    }
}

// ---------- Pass 4: one wave per segment, gather + mean ----------
__global__ __launch_bounds__(256) void gather_mean_kernel(
    const float* __restrict__ msg, const int* __restrict__ perm,
    const int* __restrict__ off, const int* __restrict__ cnt,
    float* __restrict__ out, int N) {
    int wv   = (blockIdx.x * 256 + threadIdx.x) >> 6;   // wave id == segment
    int lane = threadIdx.x & 63;
    if (wv >= N) return;

    int c = cnt[wv];
    int start = off[wv];
    const float2* m2 = (const float2*)msg;

    // Cooperative perm prefetch: one coalesced load covers up to 64 edge ids;
    // broadcast via shuffle (kills the perm-load -> row-load latency chain).
    int ep = (lane < c) ? perm[start + lane] : 0;
    int m = c < 64 ? c : 64;

    float accx = 0.f, accy = 0.f;
    int i = 0;
    // Unroll by 4: four independent 512 B row-loads in flight per wave.
    for (; i + 4 <= m; i += 4) {
        int e0 = __shfl(ep, i + 0);
        int e1 = __shfl(ep, i + 1);
        int e2 = __shfl(ep, i + 2);
        int e3 = __shfl(ep, i + 3);
        float2 a = m2[(long long)e0 * D2 + lane];
        float2 b = m2[(long long)e1 * D2 + lane];
        float2 g = m2[(long long)e2 * D2 + lane];
        float2 h = m2[(long long)e3 * D2 + lane];
        accx += (a.x + b.x) + (g.x + h.x);
        accy += (a.y + b.y) + (g.y + h.y);
    }
    for (; i < m; ++i) {
        int e0 = __shfl(ep, i);
        float2 a = m2[(long long)e0 * D2 + lane];
        accx += a.x;
        accy += a.y;
    }
    // Rare tail (c > 64): direct perm loads, still correct.
    for (; i < c; ++i) {
        int e0 = perm[start + i];
        float2 a = m2[(long long)e0 * D2 + lane];
        accx += a.x;
        accy += a.y;
    }

    float inv = 1.0f / fmaxf((float)c, 1.0f);
    float2 r;
    r.x = accx * inv;
    r.y = accy * inv;
    ((float2*)out)[(long long)wv * D2 + lane] = r;  // empty segments write 0
}

// ---------- Fallback (ws too small): round-1 atomic path ----------
__global__ __launch_bounds__(256) void scatter_add_kernel(
    const float* __restrict__ msg, const int* __restrict__ index,
    float* __restrict__ out, float* __restrict__ counts, int E) {
    long long gid = (long long)blockIdx.x * blockDim.x + threadIdx.x;
    int edge = (int)(gid >> 5);
    int lane = (int)(gid & 31);
    if (edge >= E) return;
    int seg = index[edge];
    const float4* msg4 = (const float4*)msg;
    float4 v = msg4[(long long)edge * D4 + lane];
    float* o = out + (long long)seg * D + lane * 4;
    atomicAdd(o + 0, v.x);
    atomicAdd(o + 1, v.y);
    atomicAdd(o + 2, v.z);
    atomicAdd(o + 3, v.w);
    if (lane == 0) atomicAdd(counts + seg, 1.0f);
}

__global__ __launch_bounds__(256) void normalize_kernel(
    float* __restrict__ out, const float* __restrict__ counts, int N) {
    long long gid = (long long)blockIdx.x * blockDim.x + threadIdx.x;
    int n = (int)(gid >> 5);
    int lane = (int)(gid & 31);
    if (n >= N) return;
    float c = fmaxf(counts[n], 1.0f);
    float4* out4 = (float4*)out;
    long long p = (long long)n * D4 + lane;
    float4 v = out4[p];
    v.x /= c; v.y /= c; v.z /= c; v.w /= c;
    out4[p] = v;
}

extern "C" void kernel_launch(void* const* d_in, const int* in_sizes, int n_in,
                              void* d_out, int out_size, void* d_ws, size_t ws_size,
                              hipStream_t stream) {
    const float* msg   = (const float*)d_in[0];
    const int*   index = (const int*)d_in[1];   // jax default x64 off -> int32
    float* out = (float*)d_out;

    int E = in_sizes[1];          // 2,000,000
    int N = out_size / D;         // 100,000

    int Npad = (N + 1023) & ~1023;
    int NB   = (N + 1023) >> 10;  // blocks in the block-scan (<= 1024)

    size_t need = ((size_t)3 * Npad + 1024 + (size_t)E) * sizeof(int);

    if (ws_size >= need && NB <= 1024) {
        int* cnt  = (int*)d_ws;           // [Npad]
        int* off  = cnt + Npad;           // [Npad]
        int* cur  = off + Npad;           // [Npad]
        int* bsum = cur + Npad;           // [1024]
        int* perm = bsum + 1024;          // [E]

        // Workspace is poisoned each launch; only cnt needs zeroing
        // (off/cur/bsum/perm are fully written before being read).
        hipMemsetAsync(cnt, 0, (size_t)Npad * sizeof(int), stream);

        hist_kernel<<<(E + 255) / 256, 256, 0, stream>>>(index, cnt, E);
        scan_block_kernel<<<NB, 1024, 0, stream>>>(cnt, off, bsum, N);
        scan_bsum_kernel<<<1, 1024, 0, stream>>>(bsum, NB);
        scan_add_kernel<<<(N + 255) / 256, 256, 0, stream>>>(off, bsum, cur, N);
        scatter_perm_kernel<<<(E + 255) / 256, 256, 0, stream>>>(index, cur, perm, E);

        long long tot = (long long)N * 64;  // one wave (64 lanes) per segment
        gather_mean_kernel<<<(unsigned)((tot + 255) / 256), 256, 0, stream>>>(
            msg, perm, off, cnt, out, N);
    } else {
        // Fallback: round-1 atomic path (correct, slower).
        float* counts = (float*)d_ws;     // N floats
        hipMemsetAsync(out, 0, (size_t)out_size * sizeof(float), stream);
        hipMemsetAsync(counts, 0, (size_t)N * sizeof(float), stream);
        {
            long long total = (long long)E * 32;
            long long grid = (total + 255) / 256;
            scatter_add_kernel<<<(dim3)(unsigned)grid, 256, 0, stream>>>(
                msg, index, out, counts, E);
        }
        {
            long long total = (long long)N * 32;
            long long grid = (total + 255) / 256;
            normalize_kernel<<<(dim3)(unsigned)grid, 256, 0, stream>>>(out, counts, N);
        }
    }
}